// Round 11
// baseline (1533.366 us; speedup 1.0000x reference)
//
#include <hip/hip_runtime.h>
#include <hip/hip_bf16.h>
#include <math.h>

#define N_NODES 65536
#define N_EDGES 1048576
#define NB      32
#define D       64
#define NLAYERS 4
#define G       16     // dst nodes per edge-block
#define CH      32     // edges per chunk
#define AST     72     // ushort stride for bf16 LDS activation arrays (16B-aligned rows)
#define PST     68     // float stride for p / p*M overlay arrays

typedef __attribute__((ext_vector_type(8))) short short8;   // 8 bf16 in 4 VGPRs
typedef __attribute__((ext_vector_type(4))) float f32x4;

__device__ __forceinline__ float relu_f(float x){ return x > 0.f ? x : 0.f; }
__device__ __forceinline__ unsigned short bfbits(float x){
    __bf16 h = (__bf16)x;
    return __builtin_bit_cast(unsigned short, h);
}
__device__ __forceinline__ float bfval(float x){     // value after bf16 rounding
    __bf16 h = (__bf16)x;
    return (float)h;
}
__device__ __forceinline__ f32x4 mfma16(short8 a, short8 b, f32x4 c){
    return __builtin_amdgcn_mfma_f32_16x16x32_bf16(a, b, c, 0, 0, 0);
}

// ---------------- sort-by-dst machinery ----------------

__global__ void k_zero(int* __restrict__ p){
    p[blockIdx.x * 256 + threadIdx.x] = 0;
}

__global__ void k_hist(const int* __restrict__ dst, int* __restrict__ deg){
    int e = blockIdx.x * 256 + threadIdx.x;
    if (e < N_EDGES) atomicAdd(&deg[dst[e]], 1);
}

__global__ void k_scan1(const int* __restrict__ deg, int* __restrict__ part, int* __restrict__ bsum){
    __shared__ int s[256];
    int t = threadIdx.x;
    int i = blockIdx.x * 256 + t;
    int v = deg[i];
    s[t] = v; __syncthreads();
    for (int ofs = 1; ofs < 256; ofs <<= 1){
        int tv = (t >= ofs) ? s[t - ofs] : 0;
        __syncthreads();
        s[t] += tv;
        __syncthreads();
    }
    part[i] = s[t] - v;
    if (t == 255) bsum[blockIdx.x] = s[255];
}

__global__ void k_scan2(const int* __restrict__ bsum, int* __restrict__ bofs){
    __shared__ int s[256];
    int t = threadIdx.x;
    int v = bsum[t];
    s[t] = v; __syncthreads();
    for (int ofs = 1; ofs < 256; ofs <<= 1){
        int tv = (t >= ofs) ? s[t - ofs] : 0;
        __syncthreads();
        s[t] += tv;
        __syncthreads();
    }
    bofs[t] = s[t] - v;
}

__global__ void k_scan3(const int* __restrict__ part, const int* __restrict__ bofs,
                        int* __restrict__ off, int* __restrict__ cursor){
    int i = blockIdx.x * 256 + threadIdx.x;
    int o = part[i] + bofs[i >> 8];
    off[i] = o; cursor[i] = o;
    if (i == 0) off[N_NODES] = N_EDGES;
}

__global__ void k_scatter(const int* __restrict__ ei, const float* __restrict__ pos,
                          int* __restrict__ cursor, int* __restrict__ srcs,
                          float* __restrict__ pdb){
    int e = blockIdx.x * 256 + threadIdx.x;
    if (e >= N_EDGES) return;
    int s = ei[e], d = ei[N_EDGES + e];
    int p = atomicAdd(&cursor[d], 1);
    srcs[p]    = s;
    pdb[2*p]   = pos[2*d]   - pos[2*s];
    pdb[2*p+1] = pos[2*d+1] - pos[2*s+1];
}

// ---------------- weight pre-pack into MFMA B-fragment order (hi/lo) ----------------
// Per layer block (24576 ushort): [hl][mat][nb][kf][lane][8], hl-stride 12288.
// B-frag: lane holds B[k = kf*32 + (lane>>4)*8 + j][n = nb*16 + (lane&15)], j=0..7.

__global__ void k_pack(const float* __restrict__ pW2, const float* __restrict__ aW1,
                       const float* __restrict__ aW2, unsigned short* __restrict__ bpk){
    int b  = blockIdx.x;                // L*24 + mat*8 + nb*2 + kf
    int kf = b & 1, nb = (b >> 1) & 3;
    int mat = (b >> 3) % 3, L = b / 24;
    int t = threadIdx.x;
    int lane = t & 63, jj = (t >> 6) * 2;
    const float* W = (mat == 0 ? pW2 : (mat == 1 ? aW1 : aW2)) + (size_t)L * D * D;
    int n = nb * 16 + (lane & 15);
    unsigned short* dsthi = bpk + (size_t)L * 24576
                          + (((size_t)mat * 4 + nb) * 2 + kf) * 512 + lane * 8 + jj;
    #pragma unroll
    for (int u = 0; u < 2; ++u){
        int j = jj + u;
        int k = kf * 32 + (lane >> 4) * 8 + j;
        float w = W[k * D + n];
        float hv = bfval(w);
        dsthi[u]         = bfbits(w);
        dsthi[12288 + u] = bfbits(w - hv);
    }
}

// ---------------- node GEMM: v / a_s / a_d = h @ {Wl, Ws, Wd} (fp32 VALU) ----------------

__global__ __launch_bounds__(256) void k_nodegemm(
    const float* __restrict__ h,
    const float* __restrict__ Wl, const float* __restrict__ Ws, const float* __restrict__ Wd,
    float* __restrict__ v, float* __restrict__ as_, float* __restrict__ ad)
{
    __shared__ float HT[D * 68];
    int row0 = blockIdx.x * 64;
    int t = threadIdx.x;
    {
        int r  = t >> 2;
        int kb = (t & 3) * 16;
        const float4* hp = (const float4*)(h + (size_t)(row0 + r) * D + kb);
        #pragma unroll
        for (int i4 = 0; i4 < 4; ++i4){
            float4 a = hp[i4];
            HT[(kb + i4*4 + 0)*68 + r] = a.x;
            HT[(kb + i4*4 + 1)*68 + r] = a.y;
            HT[(kb + i4*4 + 2)*68 + r] = a.z;
            HT[(kb + i4*4 + 3)*68 + r] = a.w;
        }
    }
    __syncthreads();
    int tr = t >> 4, tc = t & 15;
    int r0 = tr * 4, c0 = tc * 4;
    float accl[4][4] = {}, accs[4][4] = {}, accd[4][4] = {};
    #pragma unroll 8
    for (int k = 0; k < D; ++k){
        float4 a  = *(const float4*)&HT[k*68 + r0];
        float4 bl = *(const float4*)(Wl + k*D + c0);
        float4 bs = *(const float4*)(Ws + k*D + c0);
        float4 bd = *(const float4*)(Wd + k*D + c0);
        float av[4] = {a.x, a.y, a.z, a.w};
        #pragma unroll
        for (int i = 0; i < 4; ++i){
            accl[i][0] += av[i]*bl.x; accl[i][1] += av[i]*bl.y;
            accl[i][2] += av[i]*bl.z; accl[i][3] += av[i]*bl.w;
            accs[i][0] += av[i]*bs.x; accs[i][1] += av[i]*bs.y;
            accs[i][2] += av[i]*bs.z; accs[i][3] += av[i]*bs.w;
            accd[i][0] += av[i]*bd.x; accd[i][1] += av[i]*bd.y;
            accd[i][2] += av[i]*bd.z; accd[i][3] += av[i]*bd.w;
        }
    }
    #pragma unroll
    for (int i = 0; i < 4; ++i){
        size_t o = (size_t)(row0 + r0 + i) * D + c0;
        *(float4*)(v  + o) = make_float4(accl[i][0], accl[i][1], accl[i][2], accl[i][3]);
        *(float4*)(as_+ o) = make_float4(accs[i][0], accs[i][1], accs[i][2], accs[i][3]);
        *(float4*)(ad + o) = make_float4(accd[i][0], accd[i][1], accd[i][2], accd[i][3]);
    }
}

// ---------------- fused edge kernel (MFMA, split-bf16, 3-barrier pipeline) ----------
// Per block: G=16 consecutive dst nodes, chunks of CH=32 sorted edges.
// Round-11: B4 (E->F) eliminated. Stage F ownership remapped from wave-based
// (wave w owned nodes w*4..w*4+3, lane = channel) to q-group-based: lane (q,ln)
// of wave w reduces nodes q*4..q*4+3 at column c = w*16+ln. Every Pf/PMf value
// it reads was written by ITS OWN wave in stage E (wave w computes p/pm for all
// 32 edges on columns w*16..w*16+15) -> same-wave in-order DS ordering replaces
// the barrier; F no longer waits on other waves' E. Each (node,column) is still
// accumulated by exactly one lane over the same ascending edge order -> bit-exact.
// Remaining barriers B1/B2/B3 are load-bearing (T1/U/T2 are K-contracted across
// all 64 columns, which are wave-partitioned).
// Hazard check for removed B4: F(i) reads Pf(i) (overlays U); next U write is
// C(i+1), which sits behind B1(i+1) -> all waves' F(i) complete first. Next
// Pf/PMf write is E(i+1), behind B1,B2,B3(i+1). T2 reads in E(i) precede next
// D(i+1) writes via B1+B2(i+1). Safe.

__device__ __forceinline__ void load_bfrag(const unsigned short* __restrict__ bpk,
                                           int g, int w, int lane,
                                           short8& Bh0, short8& Bh1,
                                           short8& Bl0, short8& Bl1)
{
    int bo = ((g*4 + w)*2)*512 + lane*8;
    asm volatile("" : "+v"(bo));   // force per-stage reload; keeps B live-range inside the stage
    Bh0 = __builtin_bit_cast(short8, *(const uint4*)(bpk + bo));
    Bh1 = __builtin_bit_cast(short8, *(const uint4*)(bpk + bo + 512));
    Bl0 = __builtin_bit_cast(short8, *(const uint4*)(bpk + 12288 + bo));
    Bl1 = __builtin_bit_cast(short8, *(const uint4*)(bpk + 12288 + bo + 512));
}

__device__ __forceinline__ void gemm_tile2(const unsigned short* __restrict__ Ah,
                                           const unsigned short* __restrict__ Al,
                                           short8 Bh0, short8 Bh1, short8 Bl0, short8 Bl1,
                                           int ln, int q, f32x4* accs)
{
    #pragma unroll
    for (int mt = 0; mt < 2; ++mt){
        int ro = (mt*16 + ln) * AST;
        short8 ah0 = __builtin_bit_cast(short8, *(const uint4*)(Ah + ro + q*8));
        short8 ah1 = __builtin_bit_cast(short8, *(const uint4*)(Ah + ro + 32 + q*8));
        short8 al0 = __builtin_bit_cast(short8, *(const uint4*)(Al + ro + q*8));
        short8 al1 = __builtin_bit_cast(short8, *(const uint4*)(Al + ro + 32 + q*8));
        f32x4 acc = {0.f, 0.f, 0.f, 0.f};
        acc = mfma16(ah0, Bh0, acc);
        acc = mfma16(ah1, Bh1, acc);
        acc = mfma16(al0, Bh0, acc);
        acc = mfma16(al1, Bh1, acc);
        acc = mfma16(ah0, Bl0, acc);
        acc = mfma16(ah1, Bl1, acc);
        accs[mt] = acc;
    }
}

__global__ __launch_bounds__(256) void k_edge(
    const int* __restrict__ off, const int* __restrict__ srcs, const float* __restrict__ pdb,
    const float* __restrict__ v, const float* __restrict__ as_, const float* __restrict__ ad,
    const float* __restrict__ pW1, const float* __restrict__ pb1, const float* __restrict__ pb2,
    const float* __restrict__ ab1, const float* __restrict__ ab2,
    const unsigned short* __restrict__ bpk,   // this layer's packed B-frags
    float* __restrict__ hout)
{
    // 36.6 KB total -> 4 blocks/CU (same as the VGPR-imposed cap; LDS was slack)
    __shared__ __align__(16) unsigned short T1LDS[2 * CH * AST]; // t1 hi|lo (AB-w, C-r)
    __shared__ __align__(16) unsigned short ULDS [2 * CH * AST]; // u  hi|lo (C-w, D-r); Pf overlay (E-w, F-r)
    __shared__ __align__(16) unsigned short T2LDS[2 * CH * AST]; // t2 hi|lo (D-w, E-r)
    __shared__ __align__(16) float          PMLDS[CH * PST];     // pm       (E-w, F-r)
    __shared__ int s_sp[CH];      // src | (node-local l << 16)
    __shared__ int s_off[20];

    unsigned short* T1hi = T1LDS;
    unsigned short* T1lo = T1LDS + CH * AST;
    unsigned short* Uhi  = ULDS;
    unsigned short* Ulo  = ULDS + CH * AST;
    unsigned short* T2hi = T2LDS;
    unsigned short* T2lo = T2LDS + CH * AST;
    float* Pf  = (float*)ULDS;    // p  (stride PST) — overlays u, which is dead after D
    float* PMf = PMLDS;           // pm (stride PST) — dedicated

    int t  = threadIdx.x;
    int n0 = blockIdx.x * G;
    if (t <= G) s_off[t] = off[n0 + t];
    __syncthreads();
    int e_begin = s_off[0], e_end = s_off[G];

    int w = t >> 6, lane = t & 63;
    int q = lane >> 4, ln = lane & 15;
    int c = w * 16 + ln;                // this wave's output-column slice

    float pb2c = pb2[c], ab1c = ab1[c], ab2c = ab2[c];

    // stage-F ownership: lane (q,ln) reduces nodes q*4..q*4+3 at column c
    float den[4] = {0.f, 0.f, 0.f, 0.f};
    float num[4] = {0.f, 0.f, 0.f, 0.f};

    for (int ec = e_begin; ec < e_end; ec += CH){
        int cnt = min(CH, e_end - ec);
        // ---- stage AB: edge metadata + t1 = relu(pd @ pW1 + pb1) -> T1hi/T1lo [e][k]
        //      (overlaps the PREVIOUS chunk's stage E/F: AB touches only T1/s_sp)
        {
            int e8 = t >> 3, kb = (t & 7) * 8;
            int g = ec + ((e8 < cnt) ? e8 : 0);
            if (t < CH){
                int gg = ec + ((t < cnt) ? t : 0);
                int s = srcs[gg];
                int l = 0;
                while (l < G-1 && gg >= s_off[l+1]) ++l;
                s_sp[t] = s | (l << 16);
            }
            float2 pd = *(const float2*)(pdb + 2*g);
            float p0 = pd.x, p1 = pd.y;
            unsigned int hw[4], lw[4];
            #pragma unroll
            for (int i2 = 0; i2 < 4; ++i2){
                int k = kb + i2*2;
                float f0 = relu_f(fmaf(p1, pW1[D + k],     fmaf(p0, pW1[k],     pb1[k])));
                float f1 = relu_f(fmaf(p1, pW1[D + k + 1], fmaf(p0, pW1[k + 1], pb1[k + 1])));
                unsigned short h0 = bfbits(f0), h1 = bfbits(f1);
                float r0f = f0 - bfval(f0), r1f = f1 - bfval(f1);
                unsigned short l0 = bfbits(r0f), l1 = bfbits(r1f);
                hw[i2] = (unsigned int)h0 | ((unsigned int)h1 << 16);
                lw[i2] = (unsigned int)l0 | ((unsigned int)l1 << 16);
            }
            *(uint4*)&T1hi[e8*AST + kb] = make_uint4(hw[0], hw[1], hw[2], hw[3]);
            *(uint4*)&T1lo[e8*AST + kb] = make_uint4(lw[0], lw[1], lw[2], lw[3]);
        }
        __syncthreads();                                    // B1: T1,s_sp ready
        // ---- stage C: all gathers up front (v->Mreg, as->pa, ad->pvd), GEMM1, epilogue
        float Mreg[8];
        {
            short8 Bh0, Bh1, Bl0, Bl1;
            load_bfrag(bpk, 0, w, lane, Bh0, Bh1, Bl0, Bl1);
            float pa[8], pvd[8];
            #pragma unroll
            for (int mt = 0; mt < 2; ++mt)
                #pragma unroll
                for (int r = 0; r < 4; ++r){
                    int i = mt*4 + r;
                    int e = mt*16 + q*4 + r;
                    int sp = s_sp[e];
                    int s  = sp & 0xFFFF;
                    int dn = n0 + (sp >> 16);
                    Mreg[i] = v  [(size_t)s * D + c];
                    pa[i]   = as_[(size_t)s * D + c];
                    pvd[i]  = ad [(size_t)dn * D + c];
                }
            f32x4 accs[2];
            gemm_tile2(T1hi, T1lo, Bh0, Bh1, Bl0, Bl1, ln, q, accs);
            #pragma unroll
            for (int mt = 0; mt < 2; ++mt){
                #pragma unroll
                for (int r = 0; r < 4; ++r){
                    int i = mt*4 + r;
                    int e = mt*16 + q*4 + r;
                    float dlt = relu_f(accs[mt][r] + pb2c);
                    float uu = pvd[i] - pa[i] + dlt;
                    Mreg[i] += dlt;
                    Uhi[e*AST + c] = bfbits(uu);
                    Ulo[e*AST + c] = bfbits(uu - bfval(uu));
                }
            }
        }
        __syncthreads();                                    // B2: U ready
        // ---- stage D: GEMM2 (u @ aW1) -> t2 -> T2hi/T2lo (own buffer)
        {
            short8 Bh0, Bh1, Bl0, Bl1;
            load_bfrag(bpk, 1, w, lane, Bh0, Bh1, Bl0, Bl1);
            f32x4 accs[2];
            gemm_tile2(Uhi, Ulo, Bh0, Bh1, Bl0, Bl1, ln, q, accs);
            #pragma unroll
            for (int mt = 0; mt < 2; ++mt){
                #pragma unroll
                for (int r = 0; r < 4; ++r){
                    int e = mt*16 + q*4 + r;
                    float t2 = relu_f(accs[mt][r] + ab1c);
                    T2hi[e*AST + c] = bfbits(t2);
                    T2lo[e*AST + c] = bfbits(t2 - bfval(t2));
                }
            }
        }
        __syncthreads();                                    // B3: T2 ready
        // ---- stage E: GEMM3 (t2 @ aW2) -> alpha; p -> Pf (over u, dead); pm -> PMf
        //      (no barrier after: stage F reads only this wave's own writes)
        {
            short8 Bh0, Bh1, Bl0, Bl1;
            load_bfrag(bpk, 2, w, lane, Bh0, Bh1, Bl0, Bl1);
            f32x4 accs[2];
            gemm_tile2(T2hi, T2lo, Bh0, Bh1, Bl0, Bl1, ln, q, accs);
            #pragma unroll
            for (int mt = 0; mt < 2; ++mt){
                #pragma unroll
                for (int r = 0; r < 4; ++r){
                    int e = mt*16 + q*4 + r;
                    float a = relu_f(accs[mt][r] + ab2c);
                    float p = __expf(a);
                    Pf [e*PST + c] = p;
                    PMf[e*PST + c] = p * Mreg[mt*4 + r];
                }
            }
        }
        // ---- stage F: per-(node,column) reduction, SAME-WAVE data only.
        //      lane (q,ln) owns nodes q*4..q*4+3 at column c = w*16+ln.
        #pragma unroll
        for (int qn = 0; qn < 4; ++qn){
            int l  = q*4 + qn;
            int gs = max(s_off[l], ec);
            int ge = min(s_off[l+1], ec + cnt);
            float dd = den[qn], nn = num[qn];
            for (int g = gs; g < ge; ++g){
                int e = g - ec;
                dd += Pf [e*PST + c];
                nn += PMf[e*PST + c];
            }
            den[qn] = dd; num[qn] = nn;
        }
    }
    #pragma unroll
    for (int qn = 0; qn < 4; ++qn){
        int n = n0 + q*4 + qn;
        hout[(size_t)n * D + c] = num[qn] / den[qn];
    }
}

// ---------------- pooling + classifier ----------------

__global__ __launch_bounds__(256) void k_pool(const float* __restrict__ h,
                                              const float* __restrict__ outW,
                                              const float* __restrict__ outb,
                                              float* __restrict__ out)
{
    __shared__ float sm[4][64];
    __shared__ float sp[2][64];
    int b = blockIdx.x;
    int t = threadIdx.x, j = t & 63, g = t >> 6;
    float mx = -1e30f;
    for (int r = b*2048 + g; r < (b+1)*2048; r += 4)
        mx = fmaxf(mx, h[(size_t)r * D + j]);
    sm[g][j] = mx;
    __syncthreads();
    if (t < 64){
        float m = fmaxf(fmaxf(sm[0][j], sm[1][j]), fmaxf(sm[2][j], sm[3][j]));
        sp[0][j] = m * outW[j*2 + 0];
        sp[1][j] = m * outW[j*2 + 1];
    }
    __syncthreads();
    if (t == 0){
        float s0 = outb[0], s1 = outb[1];
        for (int k = 0; k < 64; ++k){ s0 += sp[0][k]; s1 += sp[1][k]; }
        out[b*2]   = s0;
        out[b*2+1] = s1;
    }
}

// ---------------- launch ----------------

extern "C" void kernel_launch(void* const* d_in, const int* in_sizes, int n_in,
                              void* d_out, int out_size, void* d_ws, size_t ws_size,
                              hipStream_t stream)
{
    const float* x    = (const float*)d_in[0];
    const float* pos  = (const float*)d_in[1];
    const float* Wl   = (const float*)d_in[2];
    const float* Ws   = (const float*)d_in[3];
    const float* Wd   = (const float*)d_in[4];
    const float* pW1  = (const float*)d_in[5];
    const float* pb1  = (const float*)d_in[6];
    const float* pW2  = (const float*)d_in[7];
    const float* pb2  = (const float*)d_in[8];
    const float* aW1  = (const float*)d_in[9];
    const float* ab1  = (const float*)d_in[10];
    const float* aW2  = (const float*)d_in[11];
    const float* ab2  = (const float*)d_in[12];
    const float* outW = (const float*)d_in[13];
    const float* outb = (const float*)d_in[14];
    const int*   ei   = (const int*)d_in[15];
    float* out = (float*)d_out;

    char* wp = (char*)d_ws;
    auto alloc = [&](size_t bytes){
        void* p = (void*)wp;
        wp += (bytes + 255) & ~(size_t)255;
        return p;
    };
    int*   deg    = (int*)  alloc((size_t)N_NODES * 4);
    int*   part   = (int*)  alloc((size_t)N_NODES * 4);
    int*   bsum   = (int*)  alloc(1024);
    int*   bofs   = (int*)  alloc(1024);
    int*   off    = (int*)  alloc((size_t)(N_NODES + 1) * 4);
    int*   cursor = (int*)  alloc((size_t)N_NODES * 4);
    int*   srcs   = (int*)  alloc((size_t)N_EDGES * 4);
    float* pdb    = (float*)alloc((size_t)N_EDGES * 8);
    float* vv     = (float*)alloc((size_t)N_NODES * D * 4);
    float* as_    = (float*)alloc((size_t)N_NODES * D * 4);
    float* ad     = (float*)alloc((size_t)N_NODES * D * 4);
    float* h0     = (float*)alloc((size_t)N_NODES * D * 4);
    float* h1     = (float*)alloc((size_t)N_NODES * D * 4);
    unsigned short* bpk = (unsigned short*)alloc((size_t)NLAYERS * 24576 * 2);

    // sort edges by dst (counting sort)
    k_zero   <<<256,  256, 0, stream>>>(deg);
    k_hist   <<<4096, 256, 0, stream>>>(ei + N_EDGES, deg);
    k_scan1  <<<256,  256, 0, stream>>>(deg, part, bsum);
    k_scan2  <<<1,    256, 0, stream>>>(bsum, bofs);
    k_scan3  <<<256,  256, 0, stream>>>(part, bofs, off, cursor);
    k_scatter<<<4096, 256, 0, stream>>>(ei, pos, cursor, srcs, pdb);
    k_pack   <<<96,   256, 0, stream>>>(pW2, aW1, aW2, bpk);

    const float* hin = x;
    float* hbuf[2] = { h0, h1 };
    for (int L = 0; L < NLAYERS; ++L){
        float* hout = hbuf[L & 1];
        k_nodegemm<<<N_NODES/64, 256, 0, stream>>>(hin,
            Wl + (size_t)L*D*D, Ws + (size_t)L*D*D, Wd + (size_t)L*D*D,
            vv, as_, ad);
        k_edge<<<N_NODES/G, 256, 0, stream>>>(off, srcs, pdb, vv, as_, ad,
            pW1 + (size_t)L*2*D, pb1 + (size_t)L*D, pb2 + (size_t)L*D,
            ab1 + (size_t)L*D, ab2 + (size_t)L*D,
            bpk + (size_t)L*24576,
            hout);
        hin = hout;
    }
    k_pool<<<NB, 256, 0, stream>>>(hin, outW, outb, out);
}

// Round 12
// 1452.384 us; speedup vs baseline: 1.0558x; 1.0558x over previous
//
#include <hip/hip_runtime.h>
#include <hip/hip_bf16.h>
#include <math.h>

#define N_NODES 65536
#define N_EDGES 1048576
#define NB      32
#define D       64
#define NLAYERS 4
#define G       16     // dst nodes per edge-block
#define CH      32     // edges per chunk
#define AST     72     // ushort stride for bf16 LDS activation arrays (16B-aligned rows)
#define PST     68     // float stride for p / p*M overlay arrays

typedef __attribute__((ext_vector_type(8))) short short8;   // 8 bf16 in 4 VGPRs
typedef __attribute__((ext_vector_type(4))) float f32x4;

__device__ __forceinline__ float relu_f(float x){ return x > 0.f ? x : 0.f; }
__device__ __forceinline__ unsigned short bfbits(float x){
    __bf16 h = (__bf16)x;
    return __builtin_bit_cast(unsigned short, h);
}
__device__ __forceinline__ float bfval(float x){     // value after bf16 rounding
    __bf16 h = (__bf16)x;
    return (float)h;
}
__device__ __forceinline__ f32x4 mfma16(short8 a, short8 b, f32x4 c){
    return __builtin_amdgcn_mfma_f32_16x16x32_bf16(a, b, c, 0, 0, 0);
}

// ---------------- sort-by-dst machinery ----------------

__global__ void k_zero(int* __restrict__ p){
    p[blockIdx.x * 256 + threadIdx.x] = 0;
}

__global__ void k_hist(const int* __restrict__ dst, int* __restrict__ deg){
    int e = blockIdx.x * 256 + threadIdx.x;
    if (e < N_EDGES) atomicAdd(&deg[dst[e]], 1);
}

__global__ void k_scan1(const int* __restrict__ deg, int* __restrict__ part, int* __restrict__ bsum){
    __shared__ int s[256];
    int t = threadIdx.x;
    int i = blockIdx.x * 256 + t;
    int v = deg[i];
    s[t] = v; __syncthreads();
    for (int ofs = 1; ofs < 256; ofs <<= 1){
        int tv = (t >= ofs) ? s[t - ofs] : 0;
        __syncthreads();
        s[t] += tv;
        __syncthreads();
    }
    part[i] = s[t] - v;
    if (t == 255) bsum[blockIdx.x] = s[255];
}

__global__ void k_scan2(const int* __restrict__ bsum, int* __restrict__ bofs){
    __shared__ int s[256];
    int t = threadIdx.x;
    int v = bsum[t];
    s[t] = v; __syncthreads();
    for (int ofs = 1; ofs < 256; ofs <<= 1){
        int tv = (t >= ofs) ? s[t - ofs] : 0;
        __syncthreads();
        s[t] += tv;
        __syncthreads();
    }
    bofs[t] = s[t] - v;
}

__global__ void k_scan3(const int* __restrict__ part, const int* __restrict__ bofs,
                        int* __restrict__ off, int* __restrict__ cursor){
    int i = blockIdx.x * 256 + threadIdx.x;
    int o = part[i] + bofs[i >> 8];
    off[i] = o; cursor[i] = o;
    if (i == 0) off[N_NODES] = N_EDGES;
}

__global__ void k_scatter(const int* __restrict__ ei, const float* __restrict__ pos,
                          int* __restrict__ cursor, int* __restrict__ srcs,
                          float* __restrict__ pdb){
    int e = blockIdx.x * 256 + threadIdx.x;
    if (e >= N_EDGES) return;
    int s = ei[e], d = ei[N_EDGES + e];
    int p = atomicAdd(&cursor[d], 1);
    srcs[p]    = s;
    pdb[2*p]   = pos[2*d]   - pos[2*s];
    pdb[2*p+1] = pos[2*d+1] - pos[2*s+1];
}

// ---------------- weight pre-pack into MFMA B-fragment order (hi/lo) ----------------
// Per layer block (24576 ushort): [hl][mat][nb][kf][lane][8], hl-stride 12288.
// B-frag: lane holds B[k = kf*32 + (lane>>4)*8 + j][n = nb*16 + (lane&15)], j=0..7.

__global__ void k_pack(const float* __restrict__ pW2, const float* __restrict__ aW1,
                       const float* __restrict__ aW2, unsigned short* __restrict__ bpk){
    int b  = blockIdx.x;                // L*24 + mat*8 + nb*2 + kf
    int kf = b & 1, nb = (b >> 1) & 3;
    int mat = (b >> 3) % 3, L = b / 24;
    int t = threadIdx.x;
    int lane = t & 63, jj = (t >> 6) * 2;
    const float* W = (mat == 0 ? pW2 : (mat == 1 ? aW1 : aW2)) + (size_t)L * D * D;
    int n = nb * 16 + (lane & 15);
    unsigned short* dsthi = bpk + (size_t)L * 24576
                          + (((size_t)mat * 4 + nb) * 2 + kf) * 512 + lane * 8 + jj;
    #pragma unroll
    for (int u = 0; u < 2; ++u){
        int j = jj + u;
        int k = kf * 32 + (lane >> 4) * 8 + j;
        float w = W[k * D + n];
        float hv = bfval(w);
        dsthi[u]         = bfbits(w);
        dsthi[12288 + u] = bfbits(w - hv);
    }
}

// ---------------- node GEMM: v / a_s / a_d = h @ {Wl, Ws, Wd} (fp32 VALU) ----------------

__global__ __launch_bounds__(256) void k_nodegemm(
    const float* __restrict__ h,
    const float* __restrict__ Wl, const float* __restrict__ Ws, const float* __restrict__ Wd,
    float* __restrict__ v, float* __restrict__ as_, float* __restrict__ ad)
{
    __shared__ float HT[D * 68];
    int row0 = blockIdx.x * 64;
    int t = threadIdx.x;
    {
        int r  = t >> 2;
        int kb = (t & 3) * 16;
        const float4* hp = (const float4*)(h + (size_t)(row0 + r) * D + kb);
        #pragma unroll
        for (int i4 = 0; i4 < 4; ++i4){
            float4 a = hp[i4];
            HT[(kb + i4*4 + 0)*68 + r] = a.x;
            HT[(kb + i4*4 + 1)*68 + r] = a.y;
            HT[(kb + i4*4 + 2)*68 + r] = a.z;
            HT[(kb + i4*4 + 3)*68 + r] = a.w;
        }
    }
    __syncthreads();
    int tr = t >> 4, tc = t & 15;
    int r0 = tr * 4, c0 = tc * 4;
    float accl[4][4] = {}, accs[4][4] = {}, accd[4][4] = {};
    #pragma unroll 8
    for (int k = 0; k < D; ++k){
        float4 a  = *(const float4*)&HT[k*68 + r0];
        float4 bl = *(const float4*)(Wl + k*D + c0);
        float4 bs = *(const float4*)(Ws + k*D + c0);
        float4 bd = *(const float4*)(Wd + k*D + c0);
        float av[4] = {a.x, a.y, a.z, a.w};
        #pragma unroll
        for (int i = 0; i < 4; ++i){
            accl[i][0] += av[i]*bl.x; accl[i][1] += av[i]*bl.y;
            accl[i][2] += av[i]*bl.z; accl[i][3] += av[i]*bl.w;
            accs[i][0] += av[i]*bs.x; accs[i][1] += av[i]*bs.y;
            accs[i][2] += av[i]*bs.z; accs[i][3] += av[i]*bs.w;
            accd[i][0] += av[i]*bd.x; accd[i][1] += av[i]*bd.y;
            accd[i][2] += av[i]*bd.z; accd[i][3] += av[i]*bd.w;
        }
    }
    #pragma unroll
    for (int i = 0; i < 4; ++i){
        size_t o = (size_t)(row0 + r0 + i) * D + c0;
        *(float4*)(v  + o) = make_float4(accl[i][0], accl[i][1], accl[i][2], accl[i][3]);
        *(float4*)(as_+ o) = make_float4(accs[i][0], accs[i][1], accs[i][2], accs[i][3]);
        *(float4*)(ad + o) = make_float4(accd[i][0], accd[i][1], accd[i][2], accd[i][3]);
    }
}

// ---------------- fused edge kernel (MFMA, split-bf16, 4-barrier pipeline) ----------
// FINAL (round-10 configuration — best measured: k_edge 281.6 us, total 1463 us).
// Per block: G=16 consecutive dst nodes, chunks of CH=32 sorted edges.
// Session ledger baked into this structure:
//   - CH=32 + per-stage B-frag reload keeps live set ~68 VGPR: no scratch spill
//     (64-VGPR budgets spilled 280-370 MB/dispatch; forcing 64 via launch_bounds
//     collapsed to 32+spill, 486 us — round 9).
//   - De-overlayed buffers (t2 and pm own regions) cut 6 barriers -> 4 per chunk
//     (+5%, round 10). LDS 36.6 KB is free: blocks/CU is VGPR-capped at 4 anyway.
//   - B4 (E->F) is NOT removable: F's node-major ownership vs E's channel-major
//     production is inherently cross-wave; the same-wave remap (round 11) made F's
//     loop bounds diverge across lane groups (~128 masked iters vs 8) and cost 2x
//     what the barrier costs. B1/B2/B3 are load-bearing (K-contraction crosses
//     wave-partitioned columns).
//   - Cross-chunk register prefetch is structurally dead: hipcc drains vmcnt(0) at
//     every s_barrier (round 6). In-stage up-front gathers (here) are the max cover.
//   - Wave-autonomous (zero-barrier) variant loses to this: VGPR 124 -> 16 waves/CU
//     and per-wave serial LDS chains dominate (round 8).
// Numerics: split-bf16 hi/lo MFMA reproduces the fp32 reference bit-exactly
// (absmax 0.0 across all passing rounds).

__device__ __forceinline__ void load_bfrag(const unsigned short* __restrict__ bpk,
                                           int g, int w, int lane,
                                           short8& Bh0, short8& Bh1,
                                           short8& Bl0, short8& Bl1)
{
    int bo = ((g*4 + w)*2)*512 + lane*8;
    asm volatile("" : "+v"(bo));   // force per-stage reload; keeps B live-range inside the stage
    Bh0 = __builtin_bit_cast(short8, *(const uint4*)(bpk + bo));
    Bh1 = __builtin_bit_cast(short8, *(const uint4*)(bpk + bo + 512));
    Bl0 = __builtin_bit_cast(short8, *(const uint4*)(bpk + 12288 + bo));
    Bl1 = __builtin_bit_cast(short8, *(const uint4*)(bpk + 12288 + bo + 512));
}

__device__ __forceinline__ void gemm_tile2(const unsigned short* __restrict__ Ah,
                                           const unsigned short* __restrict__ Al,
                                           short8 Bh0, short8 Bh1, short8 Bl0, short8 Bl1,
                                           int ln, int q, f32x4* accs)
{
    #pragma unroll
    for (int mt = 0; mt < 2; ++mt){
        int ro = (mt*16 + ln) * AST;
        short8 ah0 = __builtin_bit_cast(short8, *(const uint4*)(Ah + ro + q*8));
        short8 ah1 = __builtin_bit_cast(short8, *(const uint4*)(Ah + ro + 32 + q*8));
        short8 al0 = __builtin_bit_cast(short8, *(const uint4*)(Al + ro + q*8));
        short8 al1 = __builtin_bit_cast(short8, *(const uint4*)(Al + ro + 32 + q*8));
        f32x4 acc = {0.f, 0.f, 0.f, 0.f};
        acc = mfma16(ah0, Bh0, acc);
        acc = mfma16(ah1, Bh1, acc);
        acc = mfma16(al0, Bh0, acc);
        acc = mfma16(al1, Bh1, acc);
        acc = mfma16(ah0, Bl0, acc);
        acc = mfma16(ah1, Bl1, acc);
        accs[mt] = acc;
    }
}

__global__ __launch_bounds__(256) void k_edge(
    const int* __restrict__ off, const int* __restrict__ srcs, const float* __restrict__ pdb,
    const float* __restrict__ v, const float* __restrict__ as_, const float* __restrict__ ad,
    const float* __restrict__ pW1, const float* __restrict__ pb1, const float* __restrict__ pb2,
    const float* __restrict__ ab1, const float* __restrict__ ab2,
    const unsigned short* __restrict__ bpk,   // this layer's packed B-frags
    float* __restrict__ hout)
{
    // 36.6 KB total -> 4 blocks/CU (same as the VGPR-imposed cap; LDS was slack)
    __shared__ __align__(16) unsigned short T1LDS[2 * CH * AST]; // t1 hi|lo (AB-w, C-r)
    __shared__ __align__(16) unsigned short ULDS [2 * CH * AST]; // u  hi|lo (C-w, D-r); Pf overlay (E-w, F-r)
    __shared__ __align__(16) unsigned short T2LDS[2 * CH * AST]; // t2 hi|lo (D-w, E-r)
    __shared__ __align__(16) float          PMLDS[CH * PST];     // pm       (E-w, F-r)
    __shared__ int s_sp[CH];      // src | (node-local l << 16)
    __shared__ int s_off[20];

    unsigned short* T1hi = T1LDS;
    unsigned short* T1lo = T1LDS + CH * AST;
    unsigned short* Uhi  = ULDS;
    unsigned short* Ulo  = ULDS + CH * AST;
    unsigned short* T2hi = T2LDS;
    unsigned short* T2lo = T2LDS + CH * AST;
    float* Pf  = (float*)ULDS;    // p  (stride PST) — overlays u, which is dead after D
    float* PMf = PMLDS;           // pm (stride PST) — dedicated

    int t  = threadIdx.x;
    int n0 = blockIdx.x * G;
    if (t <= G) s_off[t] = off[n0 + t];
    __syncthreads();
    int e_begin = s_off[0], e_end = s_off[G];

    int w = t >> 6, lane = t & 63;
    int q = lane >> 4, ln = lane & 15;
    int c = w * 16 + ln;                // this wave's output-column slice

    float pb2c = pb2[c], ab1c = ab1[c], ab2c = ab2[c];

    float den[4] = {0.f, 0.f, 0.f, 0.f};
    float num[4] = {0.f, 0.f, 0.f, 0.f};

    for (int ec = e_begin; ec < e_end; ec += CH){
        int cnt = min(CH, e_end - ec);
        // ---- stage AB: edge metadata + t1 = relu(pd @ pW1 + pb1) -> T1hi/T1lo [e][k]
        //      (overlaps the PREVIOUS chunk's stage F: AB touches only T1/s_sp)
        {
            int e8 = t >> 3, kb = (t & 7) * 8;
            int g = ec + ((e8 < cnt) ? e8 : 0);
            if (t < CH){
                int gg = ec + ((t < cnt) ? t : 0);
                int s = srcs[gg];
                int l = 0;
                while (l < G-1 && gg >= s_off[l+1]) ++l;
                s_sp[t] = s | (l << 16);
            }
            float2 pd = *(const float2*)(pdb + 2*g);
            float p0 = pd.x, p1 = pd.y;
            unsigned int hw[4], lw[4];
            #pragma unroll
            for (int i2 = 0; i2 < 4; ++i2){
                int k = kb + i2*2;
                float f0 = relu_f(fmaf(p1, pW1[D + k],     fmaf(p0, pW1[k],     pb1[k])));
                float f1 = relu_f(fmaf(p1, pW1[D + k + 1], fmaf(p0, pW1[k + 1], pb1[k + 1])));
                unsigned short h0 = bfbits(f0), h1 = bfbits(f1);
                float r0f = f0 - bfval(f0), r1f = f1 - bfval(f1);
                unsigned short l0 = bfbits(r0f), l1 = bfbits(r1f);
                hw[i2] = (unsigned int)h0 | ((unsigned int)h1 << 16);
                lw[i2] = (unsigned int)l0 | ((unsigned int)l1 << 16);
            }
            *(uint4*)&T1hi[e8*AST + kb] = make_uint4(hw[0], hw[1], hw[2], hw[3]);
            *(uint4*)&T1lo[e8*AST + kb] = make_uint4(lw[0], lw[1], lw[2], lw[3]);
        }
        __syncthreads();                                    // B1: T1,s_sp ready
        // ---- stage C: all gathers up front (v->Mreg, as->pa, ad->pvd), GEMM1, epilogue
        float Mreg[8];
        {
            short8 Bh0, Bh1, Bl0, Bl1;
            load_bfrag(bpk, 0, w, lane, Bh0, Bh1, Bl0, Bl1);
            float pa[8], pvd[8];
            #pragma unroll
            for (int mt = 0; mt < 2; ++mt)
                #pragma unroll
                for (int r = 0; r < 4; ++r){
                    int i = mt*4 + r;
                    int e = mt*16 + q*4 + r;
                    int sp = s_sp[e];
                    int s  = sp & 0xFFFF;
                    int dn = n0 + (sp >> 16);
                    Mreg[i] = v  [(size_t)s * D + c];
                    pa[i]   = as_[(size_t)s * D + c];
                    pvd[i]  = ad [(size_t)dn * D + c];
                }
            f32x4 accs[2];
            gemm_tile2(T1hi, T1lo, Bh0, Bh1, Bl0, Bl1, ln, q, accs);
            #pragma unroll
            for (int mt = 0; mt < 2; ++mt){
                #pragma unroll
                for (int r = 0; r < 4; ++r){
                    int i = mt*4 + r;
                    int e = mt*16 + q*4 + r;
                    float dlt = relu_f(accs[mt][r] + pb2c);
                    float uu = pvd[i] - pa[i] + dlt;
                    Mreg[i] += dlt;
                    Uhi[e*AST + c] = bfbits(uu);
                    Ulo[e*AST + c] = bfbits(uu - bfval(uu));
                }
            }
        }
        __syncthreads();                                    // B2: U ready
        // ---- stage D: GEMM2 (u @ aW1) -> t2 -> T2hi/T2lo (own buffer)
        {
            short8 Bh0, Bh1, Bl0, Bl1;
            load_bfrag(bpk, 1, w, lane, Bh0, Bh1, Bl0, Bl1);
            f32x4 accs[2];
            gemm_tile2(Uhi, Ulo, Bh0, Bh1, Bl0, Bl1, ln, q, accs);
            #pragma unroll
            for (int mt = 0; mt < 2; ++mt){
                #pragma unroll
                for (int r = 0; r < 4; ++r){
                    int e = mt*16 + q*4 + r;
                    float t2 = relu_f(accs[mt][r] + ab1c);
                    T2hi[e*AST + c] = bfbits(t2);
                    T2lo[e*AST + c] = bfbits(t2 - bfval(t2));
                }
            }
        }
        __syncthreads();                                    // B3: T2 ready
        // ---- stage E: GEMM3 (t2 @ aW2) -> alpha; p -> Pf (over u, dead); pm -> PMf (own)
        {
            short8 Bh0, Bh1, Bl0, Bl1;
            load_bfrag(bpk, 2, w, lane, Bh0, Bh1, Bl0, Bl1);
            f32x4 accs[2];
            gemm_tile2(T2hi, T2lo, Bh0, Bh1, Bl0, Bl1, ln, q, accs);
            #pragma unroll
            for (int mt = 0; mt < 2; ++mt){
                #pragma unroll
                for (int r = 0; r < 4; ++r){
                    int e = mt*16 + q*4 + r;
                    float a = relu_f(accs[mt][r] + ab2c);
                    float p = __expf(a);
                    Pf [e*PST + c] = p;
                    PMf[e*PST + c] = p * Mreg[mt*4 + r];
                }
            }
        }
        __syncthreads();                                    // B4: Pf,PMf ready
        // ---- stage F: per-node reduction (wave-uniform bounds; no trailing barrier —
        //      the next chunk's AB overlaps this)
        #pragma unroll
        for (int qn = 0; qn < 4; ++qn){
            int l  = w*4 + qn;
            int gs = max(s_off[l], ec);
            int ge = min(s_off[l+1], ec + cnt);
            float dd = den[qn], nn = num[qn];
            for (int g = gs; g < ge; ++g){
                int e = g - ec;
                dd += Pf [e*PST + lane];
                nn += PMf[e*PST + lane];
            }
            den[qn] = dd; num[qn] = nn;
        }
    }
    #pragma unroll
    for (int qn = 0; qn < 4; ++qn){
        int n = n0 + w*4 + qn;
        hout[(size_t)n * D + lane] = num[qn] / den[qn];
    }
}

// ---------------- pooling + classifier ----------------

__global__ __launch_bounds__(256) void k_pool(const float* __restrict__ h,
                                              const float* __restrict__ outW,
                                              const float* __restrict__ outb,
                                              float* __restrict__ out)
{
    __shared__ float sm[4][64];
    __shared__ float sp[2][64];
    int b = blockIdx.x;
    int t = threadIdx.x, j = t & 63, g = t >> 6;
    float mx = -1e30f;
    for (int r = b*2048 + g; r < (b+1)*2048; r += 4)
        mx = fmaxf(mx, h[(size_t)r * D + j]);
    sm[g][j] = mx;
    __syncthreads();
    if (t < 64){
        float m = fmaxf(fmaxf(sm[0][j], sm[1][j]), fmaxf(sm[2][j], sm[3][j]));
        sp[0][j] = m * outW[j*2 + 0];
        sp[1][j] = m * outW[j*2 + 1];
    }
    __syncthreads();
    if (t == 0){
        float s0 = outb[0], s1 = outb[1];
        for (int k = 0; k < 64; ++k){ s0 += sp[0][k]; s1 += sp[1][k]; }
        out[b*2]   = s0;
        out[b*2+1] = s1;
    }
}

// ---------------- launch ----------------

extern "C" void kernel_launch(void* const* d_in, const int* in_sizes, int n_in,
                              void* d_out, int out_size, void* d_ws, size_t ws_size,
                              hipStream_t stream)
{
    const float* x    = (const float*)d_in[0];
    const float* pos  = (const float*)d_in[1];
    const float* Wl   = (const float*)d_in[2];
    const float* Ws   = (const float*)d_in[3];
    const float* Wd   = (const float*)d_in[4];
    const float* pW1  = (const float*)d_in[5];
    const float* pb1  = (const float*)d_in[6];
    const float* pW2  = (const float*)d_in[7];
    const float* pb2  = (const float*)d_in[8];
    const float* aW1  = (const float*)d_in[9];
    const float* ab1  = (const float*)d_in[10];
    const float* aW2  = (const float*)d_in[11];
    const float* ab2  = (const float*)d_in[12];
    const float* outW = (const float*)d_in[13];
    const float* outb = (const float*)d_in[14];
    const int*   ei   = (const int*)d_in[15];
    float* out = (float*)d_out;

    char* wp = (char*)d_ws;
    auto alloc = [&](size_t bytes){
        void* p = (void*)wp;
        wp += (bytes + 255) & ~(size_t)255;
        return p;
    };
    int*   deg    = (int*)  alloc((size_t)N_NODES * 4);
    int*   part   = (int*)  alloc((size_t)N_NODES * 4);
    int*   bsum   = (int*)  alloc(1024);
    int*   bofs   = (int*)  alloc(1024);
    int*   off    = (int*)  alloc((size_t)(N_NODES + 1) * 4);
    int*   cursor = (int*)  alloc((size_t)N_NODES * 4);
    int*   srcs   = (int*)  alloc((size_t)N_EDGES * 4);
    float* pdb    = (float*)alloc((size_t)N_EDGES * 8);
    float* vv     = (float*)alloc((size_t)N_NODES * D * 4);
    float* as_    = (float*)alloc((size_t)N_NODES * D * 4);
    float* ad     = (float*)alloc((size_t)N_NODES * D * 4);
    float* h0     = (float*)alloc((size_t)N_NODES * D * 4);
    float* h1     = (float*)alloc((size_t)N_NODES * D * 4);
    unsigned short* bpk = (unsigned short*)alloc((size_t)NLAYERS * 24576 * 2);

    // sort edges by dst (counting sort)
    k_zero   <<<256,  256, 0, stream>>>(deg);
    k_hist   <<<4096, 256, 0, stream>>>(ei + N_EDGES, deg);
    k_scan1  <<<256,  256, 0, stream>>>(deg, part, bsum);
    k_scan2  <<<1,    256, 0, stream>>>(bsum, bofs);
    k_scan3  <<<256,  256, 0, stream>>>(part, bofs, off, cursor);
    k_scatter<<<4096, 256, 0, stream>>>(ei, pos, cursor, srcs, pdb);
    k_pack   <<<96,   256, 0, stream>>>(pW2, aW1, aW2, bpk);

    const float* hin = x;
    float* hbuf[2] = { h0, h1 };
    for (int L = 0; L < NLAYERS; ++L){
        float* hout = hbuf[L & 1];
        k_nodegemm<<<N_NODES/64, 256, 0, stream>>>(hin,
            Wl + (size_t)L*D*D, Ws + (size_t)L*D*D, Wd + (size_t)L*D*D,
            vv, as_, ad);
        k_edge<<<N_NODES/G, 256, 0, stream>>>(off, srcs, pdb, vv, as_, ad,
            pW1 + (size_t)L*2*D, pb1 + (size_t)L*D, pb2 + (size_t)L*D,
            ab1 + (size_t)L*D, ab2 + (size_t)L*D,
            bpk + (size_t)L*24576,
            hout);
        hin = hout;
    }
    k_pool<<<NB, 256, 0, stream>>>(hin, outW, outb, out);
}